// Round 8
// baseline (80.644 us; speedup 1.0000x reference)
//
#include <hip/hip_runtime.h>
#include <hip/hip_bf16.h>

// 32x32-tile gather, one barrier per brush.
// out[b,c,h,w] = (1/64) Σ_n Σ_p wy[h,p] Σ_q wx[w,q] patch[b,n,c,p,q]
// sigma=0.2 -> support radius 2 px => brush window <=20x20 px.
// Grid 8x8x32 blocks (2048), 256 threads = 4 waves; thread (qi=tid&15,
// pi=tid>>4) owns patch element (p=pi,q=qi) and the 4 pixels
// (tx+qi+16a, ty+pi+16b).
// Per-wave (no LDS, no barrier): brush coords in lane registers + __ballot
// survivor mask (identical across waves); per-brush invZ computed redundantly
// by every wave and distributed by intra-wave __shfl.
// Per brush: stage1 T4[wi][p] = invZy[p]*Σ_j wx_j*(patch[:,p,qlo+j]*invZx)
// via intra-wave shuffles (source lane ((p&3)<<4)+q is in-wave for both
// halves); ONE __syncthreads; stage2 takes 5 p-taps per pixel from T4.
// T4 is double-buffered: stage2 reads of brush k (buf k&1) vs stage1 writes
// of brush k+2 (same buf) are separated by brush k+1's barrier (each wave's
// reads precede its arrival at that barrier in program order).
// Shuffles always run under block-uniform control flow (doA/doB depend only
// on gx,tx) — required because ds_bpermute from exec-masked lanes is
// undefined; out-of-range contributions are weight-masked instead.
// Incremental Gaussian: w_{j+1}=w_j*u, u*=exp(-25); d0 clamped to [-3,3]
// keeps the chain finite for masked lanes (0*finite==0).

#define E25 1.3887944e-11f   // exp(-25)

__global__ __launch_bounds__(256) void brush_tile32(
        const float* __restrict__ brushes,   // [32,64,2]
        const float* __restrict__ patches,   // [32,64,3,16,16]
        float* __restrict__ out)             // [32,3,256,256]
{
    const int b    = blockIdx.z;
    const int tx   = blockIdx.x << 5;
    const int ty   = blockIdx.y << 5;
    const int tid  = threadIdx.x;
    const int lane = tid & 63;
    const int qi   = tid & 15;
    const int pi   = tid >> 4;

    // [buf][wi][p]: 2 x 32 x (16+5 pad) float4; stride 21 f4 (84 floats,
    // 84%32=20 banks) => 2-way aliasing in stage2 (free on CDNA4)
    __shared__ float4 T4[2 * 32 * 21];

    // zero the p=16..20 pads of both buffers (stage1 writes only p<16);
    // first brush's barrier orders these vs the first stage2 reads
    for (int i = tid; i < 320; i += 256) {
        const int buf = i / 160, r = i % 160;
        T4[buf * 672 + (r / 5) * 21 + 16 + (r % 5)] = make_float4(0, 0, 0, 0);
    }

    // wave-private brush table + survivor ballot (identical across waves)
    const float2 g0 = ((const float2*)brushes)[(b << 6) + lane];
    const float bx = g0.x * 256.0f, by = g0.y * 256.0f;
    const bool hit =
        (bx >= (float)tx - 9.5f) & (bx <= (float)tx + 40.5f) &
        (by >= (float)ty - 9.5f) & (by <= (float)ty + 40.5f);
    unsigned long long mask = __ballot(hit);

    float acc[2][2][3];
#pragma unroll
    for (int a = 0; a < 2; ++a)
#pragma unroll
        for (int h2 = 0; h2 < 2; ++h2)
            acc[a][h2][0] = acc[a][h2][1] = acc[a][h2][2] = 0.0f;

    int it = 0;
    while (mask) {
        const int n = __builtin_ctzll(mask);
        mask &= mask - 1;
        const float gx = __shfl(bx, n, 64);   // uniform n -> readlane
        const float gy = __shfl(by, n, 64);
        const int buf = (it & 1) * 672; ++it;

        // patch loads in flight across the invZ computation
        const float* pb = patches + (size_t)((b << 6) + n) * 768;
        const float r0 = pb[tid];
        const float r1 = pb[tid + 256];
        const float r2 = pb[tid + 512];

        // normalizers, redundantly per wave: lane k&31 -> axis k>>4, tap k&15
        float invz;
        {
            const int k = lane & 31;
            const float g  = (k >> 4) ? gy : gx;
            const float mu = g + (float)(k & 15) - 7.5f;
            const float fl = floorf(mu);
            float Z = 0.0f;
#pragma unroll
            for (int d = -1; d <= 2; ++d) {
                const float c = fl + (float)d;
                if (c >= -8.0f && c <= 263.0f) {   // padded coord range
                    const float u = c - mu;
                    Z += __expf(-12.5f * u * u);
                }
            }
            invz = 1.0f / (Z + 1e-7f);
        }
        const float zx  = __shfl(invz, qi, 64);        // invZx[qi]
        const float zyp = __shfl(invz, 16 + pi, 64);   // invZy[pi]
        const float v0 = r0 * zx, v1 = r1 * zx, v2 = r2 * zx;

        // block-uniform half coverage (gx scalar)
        const bool doA = (gx <= (float)tx + 24.5f);   // columns tx..tx+15
        const bool doB = (gx >= (float)tx + 6.5f);    // columns tx+16..tx+31

        // ---- stage1: T4[wi][pi] for wi=qi (A) and wi=qi+16 (B) ----------
        float4 sA = make_float4(0, 0, 0, 0), sB = sA;
#pragma unroll
        for (int half = 0; half < 2; ++half) {
            const bool go = half ? doB : doA;
            if (!go) continue;                        // uniform branch
            const float ax = (float)(tx + (half << 4) + qi) - gx + 7.5f;
            const bool okx = (ax >= -2.5f) & (ax <= 17.5f);
            int qlo = (int)ceilf(ax - 2.0f);
            qlo = qlo < 0 ? 0 : (qlo > 15 ? 15 : qlo);
            float d0 = ax - (float)qlo;
            d0 = fminf(fmaxf(d0, -3.0f), 3.0f);       // keep exp chain finite
            float wgt = okx ? __expf(-12.5f * d0 * d0) : 0.0f;
            float u   = __expf(25.0f * d0 - 12.5f);
            const int base = ((pi & 3) << 4) + qlo;   // intra-wave src lane
            float4 s = make_float4(0, 0, 0, 0);
#pragma unroll
            for (int j = 0; j < 5; ++j) {
                const float a0 = __shfl(v0, base + j, 64);  // all lanes active
                const float a1 = __shfl(v1, base + j, 64);
                const float a2 = __shfl(v2, base + j, 64);
                const float wj = (qlo + j < 16) ? wgt : 0.0f;
                s.x += wj * a0; s.y += wj * a1; s.z += wj * a2;
                wgt *= u; u *= E25;
            }
            s.x *= zyp; s.y *= zyp; s.z *= zyp;
            if (half) sB = s; else sA = s;
        }
        T4[buf + qi * 21 + pi]        = sA;
        T4[buf + (qi + 16) * 21 + pi] = sB;
        __syncthreads();                              // the one barrier

        // ---- stage2: 4 pixels/thread, 5 p-taps each ---------------------
#pragma unroll
        for (int h2 = 0; h2 < 2; ++h2) {
            const float ay = (float)(ty + (h2 << 4) + pi) - gy + 7.5f;
            if (ay < -2.5f || ay > 17.5f) continue;   // divergent ok: LDS only
            int plo = (int)ceilf(ay - 2.0f);
            plo = plo < 0 ? 0 : (plo > 15 ? 15 : plo);
            const float d0 = ay - (float)plo;         // in [-2.5, 2.5]
            float wy[5];
            float wgt = __expf(-12.5f * d0 * d0);
            float u   = __expf(25.0f * d0 - 12.5f);
#pragma unroll
            for (int j = 0; j < 5; ++j) { wy[j] = wgt; wgt *= u; u *= E25; }
#pragma unroll
            for (int a = 0; a < 2; ++a) {
                if (!(a ? doB : doA)) continue;
                const float4* row = &T4[buf + (qi + (a << 4)) * 21 + plo];
                float s0 = 0.0f, s1 = 0.0f, s2 = 0.0f;
#pragma unroll
                for (int j = 0; j < 5; ++j) {
                    const float4 v = row[j];
                    s0 += wy[j] * v.x; s1 += wy[j] * v.y; s2 += wy[j] * v.z;
                }
                acc[a][h2][0] += s0; acc[a][h2][1] += s1; acc[a][h2][2] += s2;
            }
        }
        // next brush writes the other buffer; same-buffer WAR is separated
        // by the intervening brush's barrier (see header comment)
    }

    const float sc = 1.0f / 64.0f;
#pragma unroll
    for (int a = 0; a < 2; ++a)
#pragma unroll
        for (int h2 = 0; h2 < 2; ++h2) {
            const int w = tx + (a << 4) + qi;
            const int h = ty + (h2 << 4) + pi;
            float* ob = out + (((size_t)(b * 3)) << 16) + (h << 8) + w;
            ob[0]       = acc[a][h2][0] * sc;
            ob[1 << 16] = acc[a][h2][1] * sc;
            ob[2 << 16] = acc[a][h2][2] * sc;
        }
}

extern "C" void kernel_launch(void* const* d_in, const int* in_sizes, int n_in,
                              void* d_out, int out_size, void* d_ws, size_t ws_size,
                              hipStream_t stream) {
    const float* brushes = (const float*)d_in[0];
    const float* patches = (const float*)d_in[1];
    float* out = (float*)d_out;
    brush_tile32<<<dim3(8, 8, 32), dim3(256), 0, stream>>>(brushes, patches, out);
}